// Round 7
// baseline (265.545 us; speedup 1.0000x reference)
//
#include <hip/hip_runtime.h>
#include <hip/hip_bf16.h>

constexpr int NPIX = 4096;   // H*W
constexpr int NB   = 2;      // batch
constexpr int MS   = 8;      // m-split for attention (grid.y)
constexpr int PPITCH = 72;   // P_lds row pitch (bf16)
constexpr int NPART  = 16;   // BN partials per channel

typedef __attribute__((ext_vector_type(8))) short bf16x8;
typedef __attribute__((ext_vector_type(4))) float f32x4;

// ---------------------------------------------------------------------------
// Per-channel fused BN affine from partials: sc = rstd*g, sb = bb - mean*sc
// ---------------------------------------------------------------------------
__device__ inline float2 bn_coeff(const float* __restrict__ psum, const float* __restrict__ psq,
                                  const float* __restrict__ g, const float* __restrict__ bb, int c) {
  float s = 0.f, s2 = 0.f;
#pragma unroll
  for (int p = 0; p < NPART; ++p) {
    s  += psum[(size_t)c * NPART + p];
    s2 += psq [(size_t)c * NPART + p];
  }
  const float inv = 1.f / (NB * NPIX);
  float m = s * inv;
  float var = s2 * inv - m * m;
  float r = rsqrtf(var + 1e-5f) * g[c];
  return float2{r, bb[c] - m * r};
}

// ---------------------------------------------------------------------------
// conv1x1 fp32 + fused BN partial stats.
// CPT out-channels x PX pixels per thread. grid = (NPIX/(256*PX), Co/CPT, NB).
// ---------------------------------------------------------------------------
template <int CPT, int PX>
__global__ __launch_bounds__(256) void conv_stats_k(
    const float* __restrict__ x, const float* __restrict__ w,
    const float* __restrict__ bias, float* __restrict__ y,
    float* __restrict__ psum, float* __restrict__ psq, int Ci, int Co) {
  constexpr int XB = NPIX / (256 * PX);
  const int t  = threadIdx.x;
  const int n  = (blockIdx.x * 256 + t) * PX;
  const int d0 = blockIdx.y * CPT;
  const int b  = blockIdx.z;
  float a[CPT][PX];
#pragma unroll
  for (int j = 0; j < CPT; ++j) {
    float bv = bias ? bias[d0 + j] : 0.f;
#pragma unroll
    for (int p = 0; p < PX; ++p) a[j][p] = bv;
  }
  const float* xb = x + ((size_t)b * Ci) * NPIX + n;
  const float* wr = w + d0;
#pragma unroll 2
  for (int c = 0; c < Ci; ++c) {
    float xv[PX];
    if constexpr (PX == 2) *(float2*)xv = *(const float2*)(xb + (size_t)c * NPIX);
    else                   *(float4*)xv = *(const float4*)(xb + (size_t)c * NPIX);
#pragma unroll
    for (int j = 0; j < CPT; ++j) {
      float wj = wr[j];
#pragma unroll
      for (int p = 0; p < PX; ++p) a[j][p] += xv[p] * wj;
    }
    wr += Co;
  }
  float* yb = y + ((size_t)b * Co + d0) * NPIX + n;
#pragma unroll
  for (int j = 0; j < CPT; ++j) {
    if constexpr (PX == 2) *(float2*)(yb + (size_t)j * NPIX) = *(float2*)a[j];
    else                   *(float4*)(yb + (size_t)j * NPIX) = *(float4*)a[j];
  }

  float s[CPT], s2[CPT];
#pragma unroll
  for (int j = 0; j < CPT; ++j) {
    s[j] = 0.f; s2[j] = 0.f;
#pragma unroll
    for (int p = 0; p < PX; ++p) { s[j] += a[j][p]; s2[j] += a[j][p] * a[j][p]; }
  }
#pragma unroll
  for (int j = 0; j < CPT; ++j) {
    for (int d = 1; d < 64; d <<= 1) {
      s[j]  += __shfl_xor(s[j], d);
      s2[j] += __shfl_xor(s2[j], d);
    }
  }
  __shared__ float shA[4][CPT];
  __shared__ float shB[4][CPT];
  const int wave = t >> 6, lane = t & 63;
  if (lane == 0) {
#pragma unroll
    for (int j = 0; j < CPT; ++j) { shA[wave][j] = s[j]; shB[wave][j] = s2[j]; }
  }
  __syncthreads();
  if (t < CPT) {
    const int p = b * XB + blockIdx.x;
    psum[(size_t)(d0 + t) * NPART + p] = (shA[0][t] + shA[1][t]) + (shA[2][t] + shA[3][t]);
    psq [(size_t)(d0 + t) * NPART + p] = (shB[0][t] + shB[1][t]) + (shB[2][t] + shB[3][t]);
  }
}

// ---------------------------------------------------------------------------
// f & g convs fused, BN+ReLU applied on the fly (coeffs from partials, smem).
// Output transposed + channel-padded to 32: [B][N][32] bf16.
// ---------------------------------------------------------------------------
template <int CF>
__global__ __launch_bounds__(256) void fg_convT_k(
    const float* __restrict__ y,
    const float* __restrict__ psum, const float* __restrict__ psq,
    const float* __restrict__ bn_g, const float* __restrict__ bn_b,
    const float* __restrict__ wf, const float* __restrict__ bfv,
    const float* __restrict__ wg, const float* __restrict__ bgv,
    __hip_bfloat16* __restrict__ fqT, __hip_bfloat16* __restrict__ gqT, int Ci) {
  __shared__ float s_sc[96];
  __shared__ float s_sb[96];
  for (int c = threadIdx.x; c < Ci; c += 256) {
    float2 cf = bn_coeff(psum, psq, bn_g, bn_b, c);
    s_sc[c] = cf.x; s_sb[c] = cf.y;
  }
  __syncthreads();

  int n = blockIdx.x * 256 + threadIdx.x;
  int b = blockIdx.y;
  float fa[CF], ga[CF];
#pragma unroll
  for (int j = 0; j < CF; ++j) { fa[j] = bfv[j]; ga[j] = bgv[j]; }
  const float* xb = y + ((size_t)b * Ci) * NPIX + n;
  for (int ci = 0; ci < Ci; ci += 8) {
    float xr[8];
#pragma unroll
    for (int k = 0; k < 8; ++k)
      xr[k] = fmaxf(xb[(size_t)(ci + k) * NPIX] * s_sc[ci + k] + s_sb[ci + k], 0.f);
#pragma unroll
    for (int j = 0; j < CF; ++j) {
      float fs = 0.f, gs = 0.f;
#pragma unroll
      for (int k = 0; k < 8; ++k) {
        fs += xr[k] * wf[(size_t)(ci + k) * CF + j];
        gs += xr[k] * wg[(size_t)(ci + k) * CF + j];
      }
      fa[j] += fs; ga[j] += gs;
    }
  }
  __align__(16) __hip_bfloat16 of[32];
  __align__(16) __hip_bfloat16 og[32];
#pragma unroll
  for (int j = 0; j < 32; ++j) {
    of[j] = __float2bfloat16(j < CF ? fa[j] : 0.f);
    og[j] = __float2bfloat16(j < CF ? ga[j] : 0.f);
  }
  uint4* df = (uint4*)(fqT + ((size_t)b * NPIX + n) * 32);
  uint4* dg = (uint4*)(gqT + ((size_t)b * NPIX + n) * 32);
#pragma unroll
  for (int k = 0; k < 4; ++k) { df[k] = ((uint4*)of)[k]; dg[k] = ((uint4*)og)[k]; }
}

// ---------------------------------------------------------------------------
// h conv -> bf16, BN+ReLU on the fly (coeffs from partials, smem).
// 2 channels x 2 pixels per thread. grid = (8, Co/2, NB).
// ---------------------------------------------------------------------------
__global__ __launch_bounds__(256) void conv_bf16_k(
    const float* __restrict__ y,
    const float* __restrict__ psum, const float* __restrict__ psq,
    const float* __restrict__ bn_g, const float* __restrict__ bn_b,
    const float* __restrict__ w, const float* __restrict__ bias,
    __hip_bfloat16* __restrict__ out, int Ci, int Co) {
  __shared__ float s_sc[96];
  __shared__ float s_sb[96];
  for (int c = threadIdx.x; c < Ci; c += 256) {
    float2 cf = bn_coeff(psum, psq, bn_g, bn_b, c);
    s_sc[c] = cf.x; s_sb[c] = cf.y;
  }
  __syncthreads();

  int n  = (blockIdx.x * 256 + threadIdx.x) * 2;
  int d0 = blockIdx.y * 2;
  int b  = blockIdx.z;
  float2 a0 = {bias[d0], bias[d0]};
  float2 a1 = {bias[d0 + 1], bias[d0 + 1]};
  const float* xb = y + ((size_t)b * Ci) * NPIX + n;
  const float* wr = w + d0;
#pragma unroll 4
  for (int c = 0; c < Ci; ++c) {
    float2 xv = *(const float2*)(xb + (size_t)c * NPIX);
    float s = s_sc[c], o = s_sb[c];
    xv.x = fmaxf(xv.x * s + o, 0.f);
    xv.y = fmaxf(xv.y * s + o, 0.f);
    float w0 = wr[0], w1 = wr[1];
    a0.x += xv.x * w0; a0.y += xv.y * w0;
    a1.x += xv.x * w1; a1.y += xv.y * w1;
    wr += Co;
  }
  __hip_bfloat16* yb = out + ((size_t)b * Co + d0) * NPIX + n;
  auto st2 = [](__hip_bfloat16* p, float2 v) {
    __hip_bfloat162 t;
    t.x = __float2bfloat16(v.x); t.y = __float2bfloat16(v.y);
    *(unsigned*)p = *(unsigned*)&t;
  };
  st2(yb, a0);
  st2(yb + NPIX, a1);
}

// ---------------------------------------------------------------------------
// MFMA flash attention partial, wave-per-q-tile (no cross-wave reduction,
// no __syncthreads, wave-private P in LDS).
// Grid: (NPIX/64, MS, NB), 256 threads. Wave w owns queries [q0+16w, q0+16w+16).
// pacc layout [MS][B][CO][N], pl [MS][B][N].
// ---------------------------------------------------------------------------
template <int CO>
__global__ __launch_bounds__(256) void attn_mfma_k(
    const __hip_bfloat16* __restrict__ fqT, const __hip_bfloat16* __restrict__ gqT,
    const __hip_bfloat16* __restrict__ hq,
    float* __restrict__ pacc, float* __restrict__ pl) {
  constexpr int CSUB = CO / 16;
  __shared__ __align__(16) unsigned short Pw[4][16][PPITCH];

  const int t = threadIdx.x;
  const int wave = t >> 6, lane = t & 63, lq = lane & 15, lg = lane >> 4;
  const int ms = blockIdx.y, b = blockIdx.z;
  const int q0 = blockIdx.x * 64 + wave * 16;

  bf16x8 ff = *reinterpret_cast<const bf16x8*>(
      fqT + (((size_t)b * NPIX + q0 + lq) << 5) + lg * 8);

  f32x4 acc[CSUB];
#pragma unroll
  for (int cs = 0; cs < CSUB; ++cs) acc[cs] = f32x4{0.f, 0.f, 0.f, 0.f};
  float ls = 0.f;

  unsigned short* Pmy = &Pw[wave][0][0];
  const __hip_bfloat16* hbase = hq + ((size_t)b * CO + lq) * NPIX + lg * 8;

  const int mbeg = ms * (NPIX / MS);
  for (int mt = mbeg; mt < mbeg + NPIX / MS; mt += 64) {
    // QK: S[m][q] for 64 m x 16 q, exp, P -> wave-private LDS
#pragma unroll
    for (int msub = 0; msub < 4; ++msub) {
      bf16x8 ga = *reinterpret_cast<const bf16x8*>(
          gqT + (((size_t)b * NPIX + mt + msub * 16 + lq) << 5) + lg * 8);
      f32x4 z = {0.f, 0.f, 0.f, 0.f};
      f32x4 S = __builtin_amdgcn_mfma_f32_16x16x32_bf16(ga, ff, z, 0, 0, 0);
      float p0 = __expf(fminf(S[0], 60.f));
      float p1 = __expf(fminf(S[1], 60.f));
      float p2 = __expf(fminf(S[2], 60.f));
      float p3 = __expf(fminf(S[3], 60.f));
      ls += (p0 + p1) + (p2 + p3);
      __hip_bfloat162 t0, t1;
      t0.x = __float2bfloat16(p0); t0.y = __float2bfloat16(p1);
      t1.x = __float2bfloat16(p2); t1.y = __float2bfloat16(p3);
      uint2 wv;
      wv.x = *(unsigned*)&t0; wv.y = *(unsigned*)&t1;
      *(uint2*)(Pmy + lq * PPITCH + msub * 16 + lg * 4) = wv;
    }
    // PV: O += P * h
#pragma unroll
    for (int kc = 0; kc < 2; ++kc) {
      bf16x8 pa = *reinterpret_cast<const bf16x8*>(Pmy + lq * PPITCH + kc * 32 + lg * 8);
      const __hip_bfloat16* hp = hbase + mt + kc * 32;
#pragma unroll
      for (int cs = 0; cs < CSUB; ++cs) {
        bf16x8 hv = *reinterpret_cast<const bf16x8*>(hp + (size_t)cs * 16 * NPIX);
        acc[cs] = __builtin_amdgcn_mfma_f32_16x16x32_bf16(pa, hv, acc[cs], 0, 0, 0);
      }
    }
  }

  // exp-sum: reduce m-partials across lane groups (lg)
  ls += __shfl_xor(ls, 16);
  ls += __shfl_xor(ls, 32);
  const size_t lbase = ((size_t)ms * NB + b) * NPIX;
  if (lane < 16) pl[lbase + q0 + lq] = ls;

  // write per-wave O directly (unnormalized): c = cs*16+lq, q = q0 + 4*lg + r
  const size_t obase = (((size_t)ms * NB + b) * CO) * NPIX;
#pragma unroll
  for (int cs = 0; cs < CSUB; ++cs) {
    float4 v = {acc[cs][0], acc[cs][1], acc[cs][2], acc[cs][3]};
    *(float4*)&pacc[obase + (size_t)(cs * 16 + lq) * NPIX + q0 + 4 * lg] = v;
  }
}

// ---------------------------------------------------------------------------
// Attention combine: merge MS m-split partials, normalize, gamma + residual
// (BN+ReLU of y inline). float4 streaming.
// ---------------------------------------------------------------------------
template <int CO>
__global__ __launch_bounds__(256) void attn_combine2_k(
    const float* __restrict__ pacc, const float* __restrict__ pl,
    const float* __restrict__ y,
    const float* __restrict__ psum, const float* __restrict__ psq,
    const float* __restrict__ bn_g, const float* __restrict__ bn_b,
    const float* __restrict__ gam, float* __restrict__ xout) {
  int i4 = blockIdx.x * 256 + threadIdx.x;   // over NB*CO*NPIX/4
  int n  = (i4 & 1023) * 4;
  int bc = i4 >> 10;
  int b  = bc / CO, c = bc - b * CO;
  float4 o = {0.f, 0.f, 0.f, 0.f};
  float4 L = {0.f, 0.f, 0.f, 0.f};
#pragma unroll
  for (int m = 0; m < MS; ++m) {
    float4 pa = *(const float4*)&pacc[(((size_t)m * NB + b) * CO + c) * NPIX + n];
    float4 lv = *(const float4*)&pl[((size_t)m * NB + b) * NPIX + n];
    o.x += pa.x; o.y += pa.y; o.z += pa.z; o.w += pa.w;
    L.x += lv.x; L.y += lv.y; L.z += lv.z; L.w += lv.w;
  }
  float2 cf = bn_coeff(psum, psq, bn_g, bn_b, c);
  size_t xi = ((size_t)b * CO + c) * NPIX + n;
  float4 yv = *(const float4*)&y[xi];
  float gm = gam[0];
  float4 r;
  r.x = gm * (o.x / L.x) + fmaxf(yv.x * cf.x + cf.y, 0.f);
  r.y = gm * (o.y / L.y) + fmaxf(yv.y * cf.x + cf.y, 0.f);
  r.z = gm * (o.z / L.z) + fmaxf(yv.z * cf.x + cf.y, 0.f);
  r.w = gm * (o.w / L.w) + fmaxf(yv.w * cf.x + cf.y, 0.f);
  *(float4*)&xout[xi] = r;
}

// ---------------------------------------------------------------------------
// Final: BN apply + ReLU + GAP (float4); coeff computed inline per block.
// ---------------------------------------------------------------------------
__global__ __launch_bounds__(256) void bn_relu_gap_k(
    const float* __restrict__ y,
    const float* __restrict__ psum, const float* __restrict__ psq,
    const float* __restrict__ bn_g, const float* __restrict__ bn_b,
    float* __restrict__ out, int C) {
  int d = blockIdx.x;
  int b = blockIdx.y;
  int tid = threadIdx.x;
  float2 cf = bn_coeff(psum, psq, bn_g, bn_b, d);
  const float* yr = y + ((size_t)b * C + d) * NPIX;
  float s = 0.f;
  for (int n4 = tid; n4 < NPIX / 4; n4 += 256) {
    float4 v = *(const float4*)&yr[n4 * 4];
    s += fmaxf(v.x * cf.x + cf.y, 0.f) + fmaxf(v.y * cf.x + cf.y, 0.f) +
         fmaxf(v.z * cf.x + cf.y, 0.f) + fmaxf(v.w * cf.x + cf.y, 0.f);
  }
  __shared__ float sh[256];
  sh[tid] = s;
  __syncthreads();
  for (int st = 128; st > 0; st >>= 1) {
    if (tid < st) sh[tid] += sh[tid + st];
    __syncthreads();
  }
  if (tid == 0) out[(size_t)b * C + d] = sh[0] * (1.f / NPIX);
}

// ---------------------------------------------------------------------------
// Host side
// ---------------------------------------------------------------------------
extern "C" void kernel_launch(void* const* d_in, const int* in_sizes, int n_in,
                              void* d_out, int out_size, void* d_ws, size_t ws_size,
                              hipStream_t stream) {
  const float* x    = (const float*)d_in[0];
  const float* wfin = (const float*)d_in[34];
  const float* bnfg = (const float*)d_in[35];
  const float* bnfb = (const float*)d_in[36];

  float* ws = (float*)d_ws;
  size_t off = 0;
  float* y    = ws + off; off += (size_t)NB * 512 * NPIX;
  float* xo   = ws + off; off += (size_t)NB * 96 * NPIX;
  __hip_bfloat16* fqT = (__hip_bfloat16*)(ws + off); off += (size_t)NB * NPIX * 16;
  __hip_bfloat16* gqT = (__hip_bfloat16*)(ws + off); off += (size_t)NB * NPIX * 16;
  __hip_bfloat16* hq  = (__hip_bfloat16*)(ws + off); off += (size_t)NB * 48 * NPIX;
  float* psum = ws + off; off += 512 * NPART;
  float* psq  = ws + off; off += 512 * NPART;
  float* pl   = ws + off; off += (size_t)MS * NB * NPIX;
  float* pacc = ws + off; off += (size_t)MS * NB * NPIX * 96;

  const int Ci_arr[3] = {3, 32, 64};
  const int Co_arr[3] = {32, 64, 96};
  const float* cur = x;
  for (int i = 0; i < 3; ++i) {
    const float* const* p = (const float* const*)(d_in + 1 + i * 11);
    const float* w     = p[0];
    const float* bconv = p[1];
    const float* bn_g  = p[2];
    const float* bn_b  = p[3];
    const float* awf   = p[4];
    const float* abf   = p[5];
    const float* awg   = p[6];
    const float* abg   = p[7];
    const float* awh   = p[8];
    const float* abh   = p[9];
    const float* gam   = p[10];
    int Ci = Ci_arr[i], Co = Co_arr[i];

    conv_stats_k<2, 2><<<dim3(8, Co / 2, NB), 256, 0, stream>>>(cur, w, bconv, y, psum, psq, Ci, Co);

    if (i == 0)      fg_convT_k<4><<<dim3(NPIX / 256, NB), 256, 0, stream>>>(y, psum, psq, bn_g, bn_b, awf, abf, awg, abg, fqT, gqT, Co);
    else if (i == 1) fg_convT_k<8><<<dim3(NPIX / 256, NB), 256, 0, stream>>>(y, psum, psq, bn_g, bn_b, awf, abf, awg, abg, fqT, gqT, Co);
    else             fg_convT_k<12><<<dim3(NPIX / 256, NB), 256, 0, stream>>>(y, psum, psq, bn_g, bn_b, awf, abf, awg, abg, fqT, gqT, Co);

    conv_bf16_k<<<dim3(8, Co / 2, NB), 256, 0, stream>>>(y, psum, psq, bn_g, bn_b, awh, abh, hq, Co, Co);

    dim3 ag(NPIX / 64, MS, NB);
    if (Co == 32) {
      attn_mfma_k<32><<<ag, 256, 0, stream>>>(fqT, gqT, hq, pacc, pl);
      attn_combine2_k<32><<<(NB * 32 * NPIX) / 1024, 256, 0, stream>>>(pacc, pl, y, psum, psq, bn_g, bn_b, gam, xo);
    } else if (Co == 64) {
      attn_mfma_k<64><<<ag, 256, 0, stream>>>(fqT, gqT, hq, pacc, pl);
      attn_combine2_k<64><<<(NB * 64 * NPIX) / 1024, 256, 0, stream>>>(pacc, pl, y, psum, psq, bn_g, bn_b, gam, xo);
    } else {
      attn_mfma_k<96><<<ag, 256, 0, stream>>>(fqT, gqT, hq, pacc, pl);
      attn_combine2_k<96><<<(NB * 96 * NPIX) / 1024, 256, 0, stream>>>(pacc, pl, y, psum, psq, bn_g, bn_b, gam, xo);
    }
    cur = xo;
  }

  // final: conv(96->512, no bias) + stats, then BN+ReLU+GAP
  conv_stats_k<8, 2><<<dim3(8, 512 / 8, NB), 256, 0, stream>>>(cur, wfin, nullptr, y, psum, psq, 96, 512);
  bn_relu_gap_k<<<dim3(512, NB), 256, 0, stream>>>(y, psum, psq, bnfg, bnfb, (float*)d_out, 512);
}

// Round 8
// 256.171 us; speedup vs baseline: 1.0366x; 1.0366x over previous
//
#include <hip/hip_runtime.h>
#include <hip/hip_bf16.h>

constexpr int NPIX = 4096;   // H*W
constexpr int NB   = 2;      // batch
constexpr int MS   = 8;      // m-split for attention (grid.y)
constexpr int NPART  = 16;   // BN partials per channel

typedef __attribute__((ext_vector_type(8))) short bf16x8;
typedef __attribute__((ext_vector_type(4))) float f32x4;

// ---------------------------------------------------------------------------
// Per-channel fused BN affine from partials: sc = rstd*g, sb = bb - mean*sc
// ---------------------------------------------------------------------------
__device__ inline float2 bn_coeff(const float* __restrict__ psum, const float* __restrict__ psq,
                                  const float* __restrict__ g, const float* __restrict__ bb, int c) {
  float s = 0.f, s2 = 0.f;
#pragma unroll
  for (int p = 0; p < NPART; ++p) {
    s  += psum[(size_t)c * NPART + p];
    s2 += psq [(size_t)c * NPART + p];
  }
  const float inv = 1.f / (NB * NPIX);
  float m = s * inv;
  float var = s2 * inv - m * m;
  float r = rsqrtf(var + 1e-5f) * g[c];
  return float2{r, bb[c] - m * r};
}

// ---------------------------------------------------------------------------
// conv1x1 fp32 + fused BN partial stats.
// CPT out-channels x PX pixels per thread. grid = (NPIX/(256*PX), Co/CPT, NB).
// ---------------------------------------------------------------------------
template <int CPT, int PX>
__global__ __launch_bounds__(256) void conv_stats_k(
    const float* __restrict__ x, const float* __restrict__ w,
    const float* __restrict__ bias, float* __restrict__ y,
    float* __restrict__ psum, float* __restrict__ psq, int Ci, int Co) {
  constexpr int XB = NPIX / (256 * PX);
  const int t  = threadIdx.x;
  const int n  = (blockIdx.x * 256 + t) * PX;
  const int d0 = blockIdx.y * CPT;
  const int b  = blockIdx.z;
  float a[CPT][PX];
#pragma unroll
  for (int j = 0; j < CPT; ++j) {
    float bv = bias ? bias[d0 + j] : 0.f;
#pragma unroll
    for (int p = 0; p < PX; ++p) a[j][p] = bv;
  }
  const float* xb = x + ((size_t)b * Ci) * NPIX + n;
  const float* wr = w + d0;
#pragma unroll 2
  for (int c = 0; c < Ci; ++c) {
    float xv[PX];
    if constexpr (PX == 2) *(float2*)xv = *(const float2*)(xb + (size_t)c * NPIX);
    else                   *(float4*)xv = *(const float4*)(xb + (size_t)c * NPIX);
#pragma unroll
    for (int j = 0; j < CPT; ++j) {
      float wj = wr[j];
#pragma unroll
      for (int p = 0; p < PX; ++p) a[j][p] += xv[p] * wj;
    }
    wr += Co;
  }
  float* yb = y + ((size_t)b * Co + d0) * NPIX + n;
#pragma unroll
  for (int j = 0; j < CPT; ++j) {
    if constexpr (PX == 2) *(float2*)(yb + (size_t)j * NPIX) = *(float2*)a[j];
    else                   *(float4*)(yb + (size_t)j * NPIX) = *(float4*)a[j];
  }

  float s[CPT], s2[CPT];
#pragma unroll
  for (int j = 0; j < CPT; ++j) {
    s[j] = 0.f; s2[j] = 0.f;
#pragma unroll
    for (int p = 0; p < PX; ++p) { s[j] += a[j][p]; s2[j] += a[j][p] * a[j][p]; }
  }
#pragma unroll
  for (int j = 0; j < CPT; ++j) {
    for (int d = 1; d < 64; d <<= 1) {
      s[j]  += __shfl_xor(s[j], d);
      s2[j] += __shfl_xor(s2[j], d);
    }
  }
  __shared__ float shA[4][CPT];
  __shared__ float shB[4][CPT];
  const int wave = t >> 6, lane = t & 63;
  if (lane == 0) {
#pragma unroll
    for (int j = 0; j < CPT; ++j) { shA[wave][j] = s[j]; shB[wave][j] = s2[j]; }
  }
  __syncthreads();
  if (t < CPT) {
    const int p = b * XB + blockIdx.x;
    psum[(size_t)(d0 + t) * NPART + p] = (shA[0][t] + shA[1][t]) + (shA[2][t] + shA[3][t]);
    psq [(size_t)(d0 + t) * NPART + p] = (shB[0][t] + shB[1][t]) + (shB[2][t] + shB[3][t]);
  }
}

// ---------------------------------------------------------------------------
// f & g convs fused, BN+ReLU applied on the fly (coeffs from partials, smem).
// Output transposed + channel-padded to 32: [B][N][32] bf16.
// ---------------------------------------------------------------------------
template <int CF>
__global__ __launch_bounds__(256) void fg_convT_k(
    const float* __restrict__ y,
    const float* __restrict__ psum, const float* __restrict__ psq,
    const float* __restrict__ bn_g, const float* __restrict__ bn_b,
    const float* __restrict__ wf, const float* __restrict__ bfv,
    const float* __restrict__ wg, const float* __restrict__ bgv,
    __hip_bfloat16* __restrict__ fqT, __hip_bfloat16* __restrict__ gqT, int Ci) {
  __shared__ float s_sc[96];
  __shared__ float s_sb[96];
  for (int c = threadIdx.x; c < Ci; c += 256) {
    float2 cf = bn_coeff(psum, psq, bn_g, bn_b, c);
    s_sc[c] = cf.x; s_sb[c] = cf.y;
  }
  __syncthreads();

  int n = blockIdx.x * 256 + threadIdx.x;
  int b = blockIdx.y;
  float fa[CF], ga[CF];
#pragma unroll
  for (int j = 0; j < CF; ++j) { fa[j] = bfv[j]; ga[j] = bgv[j]; }
  const float* xb = y + ((size_t)b * Ci) * NPIX + n;
  for (int ci = 0; ci < Ci; ci += 8) {
    float xr[8];
#pragma unroll
    for (int k = 0; k < 8; ++k)
      xr[k] = fmaxf(xb[(size_t)(ci + k) * NPIX] * s_sc[ci + k] + s_sb[ci + k], 0.f);
#pragma unroll
    for (int j = 0; j < CF; ++j) {
      float fs = 0.f, gs = 0.f;
#pragma unroll
      for (int k = 0; k < 8; ++k) {
        fs += xr[k] * wf[(size_t)(ci + k) * CF + j];
        gs += xr[k] * wg[(size_t)(ci + k) * CF + j];
      }
      fa[j] += fs; ga[j] += gs;
    }
  }
  __align__(16) __hip_bfloat16 of[32];
  __align__(16) __hip_bfloat16 og[32];
#pragma unroll
  for (int j = 0; j < 32; ++j) {
    of[j] = __float2bfloat16(j < CF ? fa[j] : 0.f);
    og[j] = __float2bfloat16(j < CF ? ga[j] : 0.f);
  }
  uint4* df = (uint4*)(fqT + ((size_t)b * NPIX + n) * 32);
  uint4* dg = (uint4*)(gqT + ((size_t)b * NPIX + n) * 32);
#pragma unroll
  for (int k = 0; k < 4; ++k) { df[k] = ((uint4*)of)[k]; dg[k] = ((uint4*)og)[k]; }
}

// ---------------------------------------------------------------------------
// h conv -> bf16, BN+ReLU on the fly (coeffs from partials, smem).
// 2 channels x 2 pixels per thread. grid = (8, Co/2, NB).
// ---------------------------------------------------------------------------
__global__ __launch_bounds__(256) void conv_bf16_k(
    const float* __restrict__ y,
    const float* __restrict__ psum, const float* __restrict__ psq,
    const float* __restrict__ bn_g, const float* __restrict__ bn_b,
    const float* __restrict__ w, const float* __restrict__ bias,
    __hip_bfloat16* __restrict__ out, int Ci, int Co) {
  __shared__ float s_sc[96];
  __shared__ float s_sb[96];
  for (int c = threadIdx.x; c < Ci; c += 256) {
    float2 cf = bn_coeff(psum, psq, bn_g, bn_b, c);
    s_sc[c] = cf.x; s_sb[c] = cf.y;
  }
  __syncthreads();

  int n  = (blockIdx.x * 256 + threadIdx.x) * 2;
  int d0 = blockIdx.y * 2;
  int b  = blockIdx.z;
  float2 a0 = {bias[d0], bias[d0]};
  float2 a1 = {bias[d0 + 1], bias[d0 + 1]};
  const float* xb = y + ((size_t)b * Ci) * NPIX + n;
  const float* wr = w + d0;
#pragma unroll 4
  for (int c = 0; c < Ci; ++c) {
    float2 xv = *(const float2*)(xb + (size_t)c * NPIX);
    float s = s_sc[c], o = s_sb[c];
    xv.x = fmaxf(xv.x * s + o, 0.f);
    xv.y = fmaxf(xv.y * s + o, 0.f);
    float w0 = wr[0], w1 = wr[1];
    a0.x += xv.x * w0; a0.y += xv.y * w0;
    a1.x += xv.x * w1; a1.y += xv.y * w1;
    wr += Co;
  }
  __hip_bfloat16* yb = out + ((size_t)b * Co + d0) * NPIX + n;
  auto st2 = [](__hip_bfloat16* p, float2 v) {
    __hip_bfloat162 t;
    t.x = __float2bfloat16(v.x); t.y = __float2bfloat16(v.y);
    *(unsigned*)p = *(unsigned*)&t;
  };
  st2(yb, a0);
  st2(yb + NPIX, a1);
}

// ---------------------------------------------------------------------------
// MFMA flash attention partial, wave-per-32q, no barriers.
// Each wave: 32 queries (2 ff frags -> every ga/hv load feeds 2 MFMAs),
// m-chunk NPIX/MS, double-buffered XOR-swizzled wave-private P in LDS
// (QK of tile t+1 overlaps PV of tile t; b128 P reads bank-even).
// Grid: (NPIX/128, MS, NB), 256 threads. pacc [MS][B][CO][N], pl [MS][B][N].
// ---------------------------------------------------------------------------
template <int CO>
__global__ __launch_bounds__(256) void attn_mfma_k(
    const __hip_bfloat16* __restrict__ fqT, const __hip_bfloat16* __restrict__ gqT,
    const __hip_bfloat16* __restrict__ hq,
    float* __restrict__ pacc, float* __restrict__ pl) {
  constexpr int CSUB = CO / 16;
  // [wave][buf][row=32][64 shorts] = 32 KB; row stride 128 B, XOR-swizzled
  __shared__ __align__(16) unsigned short Pw[4][2][32][64];

  const int t = threadIdx.x;
  const int wave = t >> 6, lane = t & 63, lq = lane & 15, lg = lane >> 4;
  const int ms = blockIdx.y, b = blockIdx.z;
  const int q0 = blockIdx.x * 128 + wave * 32;

  bf16x8 ff[2];
#pragma unroll
  for (int qs = 0; qs < 2; ++qs)
    ff[qs] = *reinterpret_cast<const bf16x8*>(
        fqT + (((size_t)b * NPIX + q0 + qs * 16 + lq) << 5) + lg * 8);

  f32x4 acc[2][CSUB];
#pragma unroll
  for (int qs = 0; qs < 2; ++qs)
#pragma unroll
    for (int cs = 0; cs < CSUB; ++cs) acc[qs][cs] = f32x4{0.f, 0.f, 0.f, 0.f};
  float ls[2] = {0.f, 0.f};

  const __hip_bfloat16* hbase = hq + ((size_t)b * CO + lq) * NPIX + lg * 8;
  const int mbeg = ms * (NPIX / MS);

  for (int tile = 0; tile < (NPIX / MS) / 64; ++tile) {
    const int mt = mbeg + tile * 64;
    char* Pb = (char*)&Pw[wave][tile & 1][0][0];
    // ---- QK: S[m][q], exp, P -> swizzled LDS ----
#pragma unroll
    for (int msub = 0; msub < 4; ++msub) {
      bf16x8 ga = *reinterpret_cast<const bf16x8*>(
          gqT + (((size_t)b * NPIX + mt + msub * 16 + lq) << 5) + lg * 8);
#pragma unroll
      for (int qs = 0; qs < 2; ++qs) {
        f32x4 z = {0.f, 0.f, 0.f, 0.f};
        f32x4 S = __builtin_amdgcn_mfma_f32_16x16x32_bf16(ga, ff[qs], z, 0, 0, 0);
        float p0 = __expf(fminf(S[0], 60.f));
        float p1 = __expf(fminf(S[1], 60.f));
        float p2 = __expf(fminf(S[2], 60.f));
        float p3 = __expf(fminf(S[3], 60.f));
        ls[qs] += (p0 + p1) + (p2 + p3);
        __hip_bfloat162 t0, t1;
        t0.x = __float2bfloat16(p0); t0.y = __float2bfloat16(p1);
        t1.x = __float2bfloat16(p2); t1.y = __float2bfloat16(p3);
        uint2 wv;
        wv.x = *(unsigned*)&t0; wv.y = *(unsigned*)&t1;
        const int row = qs * 16 + lq;
        int byte = row * 128 + msub * 32 + lg * 8;
        byte ^= (row & 7) << 4;
        *(uint2*)(Pb + byte) = wv;
      }
    }
    // ---- PV: O += P * h ----
#pragma unroll
    for (int kc = 0; kc < 2; ++kc) {
      bf16x8 pa[2];
#pragma unroll
      for (int qs = 0; qs < 2; ++qs) {
        const int row = qs * 16 + lq;
        int byte = row * 128 + kc * 64 + lg * 16;
        byte ^= (row & 7) << 4;
        pa[qs] = *reinterpret_cast<const bf16x8*>(Pb + byte);
      }
      const __hip_bfloat16* hp = hbase + mt + kc * 32;
#pragma unroll
      for (int cs = 0; cs < CSUB; ++cs) {
        bf16x8 hv = *reinterpret_cast<const bf16x8*>(hp + (size_t)cs * 16 * NPIX);
#pragma unroll
        for (int qs = 0; qs < 2; ++qs)
          acc[qs][cs] = __builtin_amdgcn_mfma_f32_16x16x32_bf16(pa[qs], hv, acc[qs][cs], 0, 0, 0);
      }
    }
  }

  // exp-sum: reduce m-partials across lane groups (lg)
#pragma unroll
  for (int qs = 0; qs < 2; ++qs) {
    ls[qs] += __shfl_xor(ls[qs], 16);
    ls[qs] += __shfl_xor(ls[qs], 32);
  }
  const size_t lbase = ((size_t)ms * NB + b) * NPIX;
  if (lane < 16) {
    pl[lbase + q0 + lq]      = ls[0];
    pl[lbase + q0 + 16 + lq] = ls[1];
  }

  // write per-wave O directly (unnormalized): c = cs*16+lq, q = q0+qs*16+4*lg+r
  const size_t obase = (((size_t)ms * NB + b) * CO) * NPIX;
#pragma unroll
  for (int qs = 0; qs < 2; ++qs)
#pragma unroll
    for (int cs = 0; cs < CSUB; ++cs) {
      float4 v = {acc[qs][cs][0], acc[qs][cs][1], acc[qs][cs][2], acc[qs][cs][3]};
      *(float4*)&pacc[obase + (size_t)(cs * 16 + lq) * NPIX + q0 + qs * 16 + 4 * lg] = v;
    }
}

// ---------------------------------------------------------------------------
// Attention combine: merge MS m-split partials, normalize, gamma + residual
// (BN+ReLU of y inline). float4 streaming.
// ---------------------------------------------------------------------------
template <int CO>
__global__ __launch_bounds__(256) void attn_combine2_k(
    const float* __restrict__ pacc, const float* __restrict__ pl,
    const float* __restrict__ y,
    const float* __restrict__ psum, const float* __restrict__ psq,
    const float* __restrict__ bn_g, const float* __restrict__ bn_b,
    const float* __restrict__ gam, float* __restrict__ xout) {
  int i4 = blockIdx.x * 256 + threadIdx.x;   // over NB*CO*NPIX/4
  int n  = (i4 & 1023) * 4;
  int bc = i4 >> 10;
  int b  = bc / CO, c = bc - b * CO;
  float4 o = {0.f, 0.f, 0.f, 0.f};
  float4 L = {0.f, 0.f, 0.f, 0.f};
#pragma unroll
  for (int m = 0; m < MS; ++m) {
    float4 pa = *(const float4*)&pacc[(((size_t)m * NB + b) * CO + c) * NPIX + n];
    float4 lv = *(const float4*)&pl[((size_t)m * NB + b) * NPIX + n];
    o.x += pa.x; o.y += pa.y; o.z += pa.z; o.w += pa.w;
    L.x += lv.x; L.y += lv.y; L.z += lv.z; L.w += lv.w;
  }
  float2 cf = bn_coeff(psum, psq, bn_g, bn_b, c);
  size_t xi = ((size_t)b * CO + c) * NPIX + n;
  float4 yv = *(const float4*)&y[xi];
  float gm = gam[0];
  float4 r;
  r.x = gm * (o.x / L.x) + fmaxf(yv.x * cf.x + cf.y, 0.f);
  r.y = gm * (o.y / L.y) + fmaxf(yv.y * cf.x + cf.y, 0.f);
  r.z = gm * (o.z / L.z) + fmaxf(yv.z * cf.x + cf.y, 0.f);
  r.w = gm * (o.w / L.w) + fmaxf(yv.w * cf.x + cf.y, 0.f);
  *(float4*)&xout[xi] = r;
}

// ---------------------------------------------------------------------------
// Final: BN apply + ReLU + GAP (float4); coeff computed inline per block.
// ---------------------------------------------------------------------------
__global__ __launch_bounds__(256) void bn_relu_gap_k(
    const float* __restrict__ y,
    const float* __restrict__ psum, const float* __restrict__ psq,
    const float* __restrict__ bn_g, const float* __restrict__ bn_b,
    float* __restrict__ out, int C) {
  int d = blockIdx.x;
  int b = blockIdx.y;
  int tid = threadIdx.x;
  float2 cf = bn_coeff(psum, psq, bn_g, bn_b, d);
  const float* yr = y + ((size_t)b * C + d) * NPIX;
  float s = 0.f;
  for (int n4 = tid; n4 < NPIX / 4; n4 += 256) {
    float4 v = *(const float4*)&yr[n4 * 4];
    s += fmaxf(v.x * cf.x + cf.y, 0.f) + fmaxf(v.y * cf.x + cf.y, 0.f) +
         fmaxf(v.z * cf.x + cf.y, 0.f) + fmaxf(v.w * cf.x + cf.y, 0.f);
  }
  __shared__ float sh[256];
  sh[tid] = s;
  __syncthreads();
  for (int st = 128; st > 0; st >>= 1) {
    if (tid < st) sh[tid] += sh[tid + st];
    __syncthreads();
  }
  if (tid == 0) out[(size_t)b * C + d] = sh[0] * (1.f / NPIX);
}

// ---------------------------------------------------------------------------
// Host side
// ---------------------------------------------------------------------------
extern "C" void kernel_launch(void* const* d_in, const int* in_sizes, int n_in,
                              void* d_out, int out_size, void* d_ws, size_t ws_size,
                              hipStream_t stream) {
  const float* x    = (const float*)d_in[0];
  const float* wfin = (const float*)d_in[34];
  const float* bnfg = (const float*)d_in[35];
  const float* bnfb = (const float*)d_in[36];

  float* ws = (float*)d_ws;
  size_t off = 0;
  float* y    = ws + off; off += (size_t)NB * 512 * NPIX;
  float* xo   = ws + off; off += (size_t)NB * 96 * NPIX;
  __hip_bfloat16* fqT = (__hip_bfloat16*)(ws + off); off += (size_t)NB * NPIX * 16;
  __hip_bfloat16* gqT = (__hip_bfloat16*)(ws + off); off += (size_t)NB * NPIX * 16;
  __hip_bfloat16* hq  = (__hip_bfloat16*)(ws + off); off += (size_t)NB * 48 * NPIX;
  float* psum = ws + off; off += 512 * NPART;
  float* psq  = ws + off; off += 512 * NPART;
  float* pl   = ws + off; off += (size_t)MS * NB * NPIX;
  float* pacc = ws + off; off += (size_t)MS * NB * NPIX * 96;

  const int Ci_arr[3] = {3, 32, 64};
  const int Co_arr[3] = {32, 64, 96};
  const float* cur = x;
  for (int i = 0; i < 3; ++i) {
    const float* const* p = (const float* const*)(d_in + 1 + i * 11);
    const float* w     = p[0];
    const float* bconv = p[1];
    const float* bn_g  = p[2];
    const float* bn_b  = p[3];
    const float* awf   = p[4];
    const float* abf   = p[5];
    const float* awg   = p[6];
    const float* abg   = p[7];
    const float* awh   = p[8];
    const float* abh   = p[9];
    const float* gam   = p[10];
    int Ci = Ci_arr[i], Co = Co_arr[i];

    conv_stats_k<2, 2><<<dim3(8, Co / 2, NB), 256, 0, stream>>>(cur, w, bconv, y, psum, psq, Ci, Co);

    if (i == 0)      fg_convT_k<4><<<dim3(NPIX / 256, NB), 256, 0, stream>>>(y, psum, psq, bn_g, bn_b, awf, abf, awg, abg, fqT, gqT, Co);
    else if (i == 1) fg_convT_k<8><<<dim3(NPIX / 256, NB), 256, 0, stream>>>(y, psum, psq, bn_g, bn_b, awf, abf, awg, abg, fqT, gqT, Co);
    else             fg_convT_k<12><<<dim3(NPIX / 256, NB), 256, 0, stream>>>(y, psum, psq, bn_g, bn_b, awf, abf, awg, abg, fqT, gqT, Co);

    conv_bf16_k<<<dim3(8, Co / 2, NB), 256, 0, stream>>>(y, psum, psq, bn_g, bn_b, awh, abh, hq, Co, Co);

    dim3 ag(NPIX / 128, MS, NB);
    if (Co == 32) {
      attn_mfma_k<32><<<ag, 256, 0, stream>>>(fqT, gqT, hq, pacc, pl);
      attn_combine2_k<32><<<(NB * 32 * NPIX) / 1024, 256, 0, stream>>>(pacc, pl, y, psum, psq, bn_g, bn_b, gam, xo);
    } else if (Co == 64) {
      attn_mfma_k<64><<<ag, 256, 0, stream>>>(fqT, gqT, hq, pacc, pl);
      attn_combine2_k<64><<<(NB * 64 * NPIX) / 1024, 256, 0, stream>>>(pacc, pl, y, psum, psq, bn_g, bn_b, gam, xo);
    } else {
      attn_mfma_k<96><<<ag, 256, 0, stream>>>(fqT, gqT, hq, pacc, pl);
      attn_combine2_k<96><<<(NB * 96 * NPIX) / 1024, 256, 0, stream>>>(pacc, pl, y, psum, psq, bn_g, bn_b, gam, xo);
    }
    cur = xo;
  }

  // final: conv(96->512, no bias) + stats, then BN+ReLU+GAP
  conv_stats_k<8, 2><<<dim3(8, 512 / 8, NB), 256, 0, stream>>>(cur, wfin, nullptr, y, psum, psq, 96, 512);
  bn_relu_gap_k<<<dim3(512, NB), 256, 0, stream>>>(y, psum, psq, bnfg, bnfb, (float*)d_out, 512);
}

// Round 9
// 214.873 us; speedup vs baseline: 1.2358x; 1.1922x over previous
//
#include <hip/hip_runtime.h>
#include <hip/hip_bf16.h>

constexpr int NPIX = 4096;   // H*W
constexpr int NB   = 2;      // batch
constexpr int MS   = 8;      // m-split for attention (grid.y)
constexpr int NPART  = 16;   // BN partials per channel

typedef __attribute__((ext_vector_type(8))) short bf16x8;
typedef __attribute__((ext_vector_type(4))) float f32x4;

// ---------------------------------------------------------------------------
// Per-channel fused BN affine from partials: sc = rstd*g, sb = bb - mean*sc
// ---------------------------------------------------------------------------
__device__ inline float2 bn_coeff(const float* __restrict__ psum, const float* __restrict__ psq,
                                  const float* __restrict__ g, const float* __restrict__ bb, int c) {
  float s = 0.f, s2 = 0.f;
#pragma unroll
  for (int p = 0; p < NPART; ++p) {
    s  += psum[(size_t)c * NPART + p];
    s2 += psq [(size_t)c * NPART + p];
  }
  const float inv = 1.f / (NB * NPIX);
  float m = s * inv;
  float var = s2 * inv - m * m;
  float r = rsqrtf(var + 1e-5f) * g[c];
  return float2{r, bb[c] - m * r};
}

// ---------------------------------------------------------------------------
// conv1x1 fp32 + fused BN partial stats.
// CPT out-channels x PX pixels per thread. grid = (NPIX/(256*PX), Co/CPT, NB).
// ---------------------------------------------------------------------------
template <int CPT, int PX>
__global__ __launch_bounds__(256) void conv_stats_k(
    const float* __restrict__ x, const float* __restrict__ w,
    const float* __restrict__ bias, float* __restrict__ y,
    float* __restrict__ psum, float* __restrict__ psq, int Ci, int Co) {
  constexpr int XB = NPIX / (256 * PX);
  const int t  = threadIdx.x;
  const int n  = (blockIdx.x * 256 + t) * PX;
  const int d0 = blockIdx.y * CPT;
  const int b  = blockIdx.z;
  float a[CPT][PX];
#pragma unroll
  for (int j = 0; j < CPT; ++j) {
    float bv = bias ? bias[d0 + j] : 0.f;
#pragma unroll
    for (int p = 0; p < PX; ++p) a[j][p] = bv;
  }
  const float* xb = x + ((size_t)b * Ci) * NPIX + n;
  const float* wr = w + d0;
#pragma unroll 2
  for (int c = 0; c < Ci; ++c) {
    float xv[PX];
    if constexpr (PX == 2) *(float2*)xv = *(const float2*)(xb + (size_t)c * NPIX);
    else                   *(float4*)xv = *(const float4*)(xb + (size_t)c * NPIX);
#pragma unroll
    for (int j = 0; j < CPT; ++j) {
      float wj = wr[j];
#pragma unroll
      for (int p = 0; p < PX; ++p) a[j][p] += xv[p] * wj;
    }
    wr += Co;
  }
  float* yb = y + ((size_t)b * Co + d0) * NPIX + n;
#pragma unroll
  for (int j = 0; j < CPT; ++j) {
    if constexpr (PX == 2) *(float2*)(yb + (size_t)j * NPIX) = *(float2*)a[j];
    else                   *(float4*)(yb + (size_t)j * NPIX) = *(float4*)a[j];
  }

  float s[CPT], s2[CPT];
#pragma unroll
  for (int j = 0; j < CPT; ++j) {
    s[j] = 0.f; s2[j] = 0.f;
#pragma unroll
    for (int p = 0; p < PX; ++p) { s[j] += a[j][p]; s2[j] += a[j][p] * a[j][p]; }
  }
#pragma unroll
  for (int j = 0; j < CPT; ++j) {
    for (int d = 1; d < 64; d <<= 1) {
      s[j]  += __shfl_xor(s[j], d);
      s2[j] += __shfl_xor(s2[j], d);
    }
  }
  __shared__ float shA[4][CPT];
  __shared__ float shB[4][CPT];
  const int wave = t >> 6, lane = t & 63;
  if (lane == 0) {
#pragma unroll
    for (int j = 0; j < CPT; ++j) { shA[wave][j] = s[j]; shB[wave][j] = s2[j]; }
  }
  __syncthreads();
  if (t < CPT) {
    const int p = b * XB + blockIdx.x;
    psum[(size_t)(d0 + t) * NPART + p] = (shA[0][t] + shA[1][t]) + (shA[2][t] + shA[3][t]);
    psq [(size_t)(d0 + t) * NPART + p] = (shB[0][t] + shB[1][t]) + (shB[2][t] + shB[3][t]);
  }
}

// ---------------------------------------------------------------------------
// f & g convs fused, BN+ReLU applied on the fly (coeffs from partials, smem).
// Output transposed + channel-padded to 32: [B][N][32] bf16.
// ---------------------------------------------------------------------------
template <int CF>
__global__ __launch_bounds__(256) void fg_convT_k(
    const float* __restrict__ y,
    const float* __restrict__ psum, const float* __restrict__ psq,
    const float* __restrict__ bn_g, const float* __restrict__ bn_b,
    const float* __restrict__ wf, const float* __restrict__ bfv,
    const float* __restrict__ wg, const float* __restrict__ bgv,
    __hip_bfloat16* __restrict__ fqT, __hip_bfloat16* __restrict__ gqT, int Ci) {
  __shared__ float s_sc[96];
  __shared__ float s_sb[96];
  for (int c = threadIdx.x; c < Ci; c += 256) {
    float2 cf = bn_coeff(psum, psq, bn_g, bn_b, c);
    s_sc[c] = cf.x; s_sb[c] = cf.y;
  }
  __syncthreads();

  int n = blockIdx.x * 256 + threadIdx.x;
  int b = blockIdx.y;
  float fa[CF], ga[CF];
#pragma unroll
  for (int j = 0; j < CF; ++j) { fa[j] = bfv[j]; ga[j] = bgv[j]; }
  const float* xb = y + ((size_t)b * Ci) * NPIX + n;
  for (int ci = 0; ci < Ci; ci += 8) {
    float xr[8];
#pragma unroll
    for (int k = 0; k < 8; ++k)
      xr[k] = fmaxf(xb[(size_t)(ci + k) * NPIX] * s_sc[ci + k] + s_sb[ci + k], 0.f);
#pragma unroll
    for (int j = 0; j < CF; ++j) {
      float fs = 0.f, gs = 0.f;
#pragma unroll
      for (int k = 0; k < 8; ++k) {
        fs += xr[k] * wf[(size_t)(ci + k) * CF + j];
        gs += xr[k] * wg[(size_t)(ci + k) * CF + j];
      }
      fa[j] += fs; ga[j] += gs;
    }
  }
  __align__(16) __hip_bfloat16 of[32];
  __align__(16) __hip_bfloat16 og[32];
#pragma unroll
  for (int j = 0; j < 32; ++j) {
    of[j] = __float2bfloat16(j < CF ? fa[j] : 0.f);
    og[j] = __float2bfloat16(j < CF ? ga[j] : 0.f);
  }
  uint4* df = (uint4*)(fqT + ((size_t)b * NPIX + n) * 32);
  uint4* dg = (uint4*)(gqT + ((size_t)b * NPIX + n) * 32);
#pragma unroll
  for (int k = 0; k < 4; ++k) { df[k] = ((uint4*)of)[k]; dg[k] = ((uint4*)og)[k]; }
}

// ---------------------------------------------------------------------------
// h conv -> bf16 in h3 layout [B][N/32][CO][32] (coalesced PV B-fragments).
// BN+ReLU on the fly. 2 channels x 2 pixels per thread. grid = (8, Co/2, NB).
// ---------------------------------------------------------------------------
__global__ __launch_bounds__(256) void conv_bf16_k(
    const float* __restrict__ y,
    const float* __restrict__ psum, const float* __restrict__ psq,
    const float* __restrict__ bn_g, const float* __restrict__ bn_b,
    const float* __restrict__ w, const float* __restrict__ bias,
    __hip_bfloat16* __restrict__ out, int Ci, int Co) {
  __shared__ float s_sc[96];
  __shared__ float s_sb[96];
  for (int c = threadIdx.x; c < Ci; c += 256) {
    float2 cf = bn_coeff(psum, psq, bn_g, bn_b, c);
    s_sc[c] = cf.x; s_sb[c] = cf.y;
  }
  __syncthreads();

  int n  = (blockIdx.x * 256 + threadIdx.x) * 2;
  int d0 = blockIdx.y * 2;
  int b  = blockIdx.z;
  float2 a0 = {bias[d0], bias[d0]};
  float2 a1 = {bias[d0 + 1], bias[d0 + 1]};
  const float* xb = y + ((size_t)b * Ci) * NPIX + n;
  const float* wr = w + d0;
#pragma unroll 4
  for (int c = 0; c < Ci; ++c) {
    float2 xv = *(const float2*)(xb + (size_t)c * NPIX);
    float s = s_sc[c], o = s_sb[c];
    xv.x = fmaxf(xv.x * s + o, 0.f);
    xv.y = fmaxf(xv.y * s + o, 0.f);
    float w0 = wr[0], w1 = wr[1];
    a0.x += xv.x * w0; a0.y += xv.y * w0;
    a1.x += xv.x * w1; a1.y += xv.y * w1;
    wr += Co;
  }
  // h3 layout: [(b*(N/32) + n/32)*Co + c]*32 + (n&31)
  __hip_bfloat16* yb = out + ((size_t)(b * (NPIX / 32) + (n >> 5)) * Co + d0) * 32 + (n & 31);
  auto st2 = [](__hip_bfloat16* p, float2 v) {
    __hip_bfloat162 t;
    t.x = __float2bfloat16(v.x); t.y = __float2bfloat16(v.y);
    *(unsigned*)p = *(unsigned*)&t;
  };
  st2(yb, a0);
  st2(yb + 32, a1);
}

// ---------------------------------------------------------------------------
// MFMA flash attention partial, wave-per-32q, no barriers.
// h in h3 layout -> per-wave hv loads are 1KB contiguous; all 12 hv fragments
// prefetched at tile start so L2 latency hides under QK+exp.
// Grid: (NPIX/128, MS, NB), 256 threads. pacc [MS][B][CO][N], pl [MS][B][N].
// ---------------------------------------------------------------------------
template <int CO>
__global__ __launch_bounds__(256) void attn_mfma_k(
    const __hip_bfloat16* __restrict__ fqT, const __hip_bfloat16* __restrict__ gqT,
    const __hip_bfloat16* __restrict__ hq,
    float* __restrict__ pacc, float* __restrict__ pl) {
  constexpr int CSUB = CO / 16;
  __shared__ __align__(16) unsigned short Pw[4][2][32][64];   // 32 KB, XOR-swizzled

  const int t = threadIdx.x;
  const int wave = t >> 6, lane = t & 63, lq = lane & 15, lg = lane >> 4;
  const int ms = blockIdx.y, b = blockIdx.z;
  const int q0 = blockIdx.x * 128 + wave * 32;

  bf16x8 ff[2];
#pragma unroll
  for (int qs = 0; qs < 2; ++qs)
    ff[qs] = *reinterpret_cast<const bf16x8*>(
        fqT + (((size_t)b * NPIX + q0 + qs * 16 + lq) << 5) + lg * 8);

  f32x4 acc[2][CSUB];
#pragma unroll
  for (int qs = 0; qs < 2; ++qs)
#pragma unroll
    for (int cs = 0; cs < CSUB; ++cs) acc[qs][cs] = f32x4{0.f, 0.f, 0.f, 0.f};
  float ls[2] = {0.f, 0.f};

  // h3: [B][N/32][CO][32]
  const __hip_bfloat16* h3b = hq + (size_t)b * (NPIX / 32) * CO * 32;
  const int mbeg = ms * (NPIX / MS);

  for (int tile = 0; tile < (NPIX / MS) / 64; ++tile) {
    const int mt = mbeg + tile * 64;
    char* Pb = (char*)&Pw[wave][tile & 1][0][0];

    // ---- prefetch all hv B-fragments for this tile (coalesced, off critical path)
    bf16x8 hv[2][CSUB];
#pragma unroll
    for (int kc = 0; kc < 2; ++kc)
#pragma unroll
      for (int cs = 0; cs < CSUB; ++cs)
        hv[kc][cs] = *reinterpret_cast<const bf16x8*>(
            h3b + ((size_t)((mt >> 5) + kc) * CO + cs * 16 + lq) * 32 + lg * 8);

    // ---- QK: S[m][q], exp, P -> swizzled LDS ----
#pragma unroll
    for (int msub = 0; msub < 4; ++msub) {
      bf16x8 ga = *reinterpret_cast<const bf16x8*>(
          gqT + (((size_t)b * NPIX + mt + msub * 16 + lq) << 5) + lg * 8);
#pragma unroll
      for (int qs = 0; qs < 2; ++qs) {
        f32x4 z = {0.f, 0.f, 0.f, 0.f};
        f32x4 S = __builtin_amdgcn_mfma_f32_16x16x32_bf16(ga, ff[qs], z, 0, 0, 0);
        float p0 = __expf(fminf(S[0], 60.f));
        float p1 = __expf(fminf(S[1], 60.f));
        float p2 = __expf(fminf(S[2], 60.f));
        float p3 = __expf(fminf(S[3], 60.f));
        ls[qs] += (p0 + p1) + (p2 + p3);
        __hip_bfloat162 t0, t1;
        t0.x = __float2bfloat16(p0); t0.y = __float2bfloat16(p1);
        t1.x = __float2bfloat16(p2); t1.y = __float2bfloat16(p3);
        uint2 wv;
        wv.x = *(unsigned*)&t0; wv.y = *(unsigned*)&t1;
        const int row = qs * 16 + lq;
        int byte = row * 128 + msub * 32 + lg * 8;
        byte ^= (row & 7) << 4;
        *(uint2*)(Pb + byte) = wv;
      }
    }
    // ---- PV: O += P * h (hv already in regs) ----
#pragma unroll
    for (int kc = 0; kc < 2; ++kc) {
      bf16x8 pa[2];
#pragma unroll
      for (int qs = 0; qs < 2; ++qs) {
        const int row = qs * 16 + lq;
        int byte = row * 128 + kc * 64 + lg * 16;
        byte ^= (row & 7) << 4;
        pa[qs] = *reinterpret_cast<const bf16x8*>(Pb + byte);
      }
#pragma unroll
      for (int cs = 0; cs < CSUB; ++cs)
#pragma unroll
        for (int qs = 0; qs < 2; ++qs)
          acc[qs][cs] = __builtin_amdgcn_mfma_f32_16x16x32_bf16(pa[qs], hv[kc][cs], acc[qs][cs], 0, 0, 0);
    }
  }

  // exp-sum: reduce m-partials across lane groups (lg)
#pragma unroll
  for (int qs = 0; qs < 2; ++qs) {
    ls[qs] += __shfl_xor(ls[qs], 16);
    ls[qs] += __shfl_xor(ls[qs], 32);
  }
  const size_t lbase = ((size_t)ms * NB + b) * NPIX;
  if (lane < 16) {
    pl[lbase + q0 + lq]      = ls[0];
    pl[lbase + q0 + 16 + lq] = ls[1];
  }

  // write per-wave O directly (unnormalized): c = cs*16+lq, q = q0+qs*16+4*lg+r
  const size_t obase = (((size_t)ms * NB + b) * CO) * NPIX;
#pragma unroll
  for (int qs = 0; qs < 2; ++qs)
#pragma unroll
    for (int cs = 0; cs < CSUB; ++cs) {
      float4 v = {acc[qs][cs][0], acc[qs][cs][1], acc[qs][cs][2], acc[qs][cs][3]};
      *(float4*)&pacc[obase + (size_t)(cs * 16 + lq) * NPIX + q0 + qs * 16 + 4 * lg] = v;
    }
}

// ---------------------------------------------------------------------------
// Attention combine: merge MS m-split partials, normalize, gamma + residual
// (BN+ReLU of y inline). float4 streaming.
// ---------------------------------------------------------------------------
template <int CO>
__global__ __launch_bounds__(256) void attn_combine2_k(
    const float* __restrict__ pacc, const float* __restrict__ pl,
    const float* __restrict__ y,
    const float* __restrict__ psum, const float* __restrict__ psq,
    const float* __restrict__ bn_g, const float* __restrict__ bn_b,
    const float* __restrict__ gam, float* __restrict__ xout) {
  int i4 = blockIdx.x * 256 + threadIdx.x;   // over NB*CO*NPIX/4
  int n  = (i4 & 1023) * 4;
  int bc = i4 >> 10;
  int b  = bc / CO, c = bc - b * CO;
  float4 o = {0.f, 0.f, 0.f, 0.f};
  float4 L = {0.f, 0.f, 0.f, 0.f};
#pragma unroll
  for (int m = 0; m < MS; ++m) {
    float4 pa = *(const float4*)&pacc[(((size_t)m * NB + b) * CO + c) * NPIX + n];
    float4 lv = *(const float4*)&pl[((size_t)m * NB + b) * NPIX + n];
    o.x += pa.x; o.y += pa.y; o.z += pa.z; o.w += pa.w;
    L.x += lv.x; L.y += lv.y; L.z += lv.z; L.w += lv.w;
  }
  float2 cf = bn_coeff(psum, psq, bn_g, bn_b, c);
  size_t xi = ((size_t)b * CO + c) * NPIX + n;
  float4 yv = *(const float4*)&y[xi];
  float gm = gam[0];
  float4 r;
  r.x = gm * (o.x / L.x) + fmaxf(yv.x * cf.x + cf.y, 0.f);
  r.y = gm * (o.y / L.y) + fmaxf(yv.y * cf.x + cf.y, 0.f);
  r.z = gm * (o.z / L.z) + fmaxf(yv.z * cf.x + cf.y, 0.f);
  r.w = gm * (o.w / L.w) + fmaxf(yv.w * cf.x + cf.y, 0.f);
  *(float4*)&xout[xi] = r;
}

// ---------------------------------------------------------------------------
// Final: BN apply + ReLU + GAP (float4); coeff computed inline per block.
// ---------------------------------------------------------------------------
__global__ __launch_bounds__(256) void bn_relu_gap_k(
    const float* __restrict__ y,
    const float* __restrict__ psum, const float* __restrict__ psq,
    const float* __restrict__ bn_g, const float* __restrict__ bn_b,
    float* __restrict__ out, int C) {
  int d = blockIdx.x;
  int b = blockIdx.y;
  int tid = threadIdx.x;
  float2 cf = bn_coeff(psum, psq, bn_g, bn_b, d);
  const float* yr = y + ((size_t)b * C + d) * NPIX;
  float s = 0.f;
  for (int n4 = tid; n4 < NPIX / 4; n4 += 256) {
    float4 v = *(const float4*)&yr[n4 * 4];
    s += fmaxf(v.x * cf.x + cf.y, 0.f) + fmaxf(v.y * cf.x + cf.y, 0.f) +
         fmaxf(v.z * cf.x + cf.y, 0.f) + fmaxf(v.w * cf.x + cf.y, 0.f);
  }
  __shared__ float sh[256];
  sh[tid] = s;
  __syncthreads();
  for (int st = 128; st > 0; st >>= 1) {
    if (tid < st) sh[tid] += sh[tid + st];
    __syncthreads();
  }
  if (tid == 0) out[(size_t)b * C + d] = sh[0] * (1.f / NPIX);
}

// ---------------------------------------------------------------------------
// Host side
// ---------------------------------------------------------------------------
extern "C" void kernel_launch(void* const* d_in, const int* in_sizes, int n_in,
                              void* d_out, int out_size, void* d_ws, size_t ws_size,
                              hipStream_t stream) {
  const float* x    = (const float*)d_in[0];
  const float* wfin = (const float*)d_in[34];
  const float* bnfg = (const float*)d_in[35];
  const float* bnfb = (const float*)d_in[36];

  float* ws = (float*)d_ws;
  size_t off = 0;
  float* y    = ws + off; off += (size_t)NB * 512 * NPIX;
  float* xo   = ws + off; off += (size_t)NB * 96 * NPIX;
  __hip_bfloat16* fqT = (__hip_bfloat16*)(ws + off); off += (size_t)NB * NPIX * 16;
  __hip_bfloat16* gqT = (__hip_bfloat16*)(ws + off); off += (size_t)NB * NPIX * 16;
  __hip_bfloat16* hq  = (__hip_bfloat16*)(ws + off); off += (size_t)NB * 48 * NPIX;
  float* psum = ws + off; off += 512 * NPART;
  float* psq  = ws + off; off += 512 * NPART;
  float* pl   = ws + off; off += (size_t)MS * NB * NPIX;
  float* pacc = ws + off; off += (size_t)MS * NB * NPIX * 96;

  const int Ci_arr[3] = {3, 32, 64};
  const int Co_arr[3] = {32, 64, 96};
  const float* cur = x;
  for (int i = 0; i < 3; ++i) {
    const float* const* p = (const float* const*)(d_in + 1 + i * 11);
    const float* w     = p[0];
    const float* bconv = p[1];
    const float* bn_g  = p[2];
    const float* bn_b  = p[3];
    const float* awf   = p[4];
    const float* abf   = p[5];
    const float* awg   = p[6];
    const float* abg   = p[7];
    const float* awh   = p[8];
    const float* abh   = p[9];
    const float* gam   = p[10];
    int Ci = Ci_arr[i], Co = Co_arr[i];

    conv_stats_k<2, 2><<<dim3(8, Co / 2, NB), 256, 0, stream>>>(cur, w, bconv, y, psum, psq, Ci, Co);

    if (i == 0)      fg_convT_k<4><<<dim3(NPIX / 256, NB), 256, 0, stream>>>(y, psum, psq, bn_g, bn_b, awf, abf, awg, abg, fqT, gqT, Co);
    else if (i == 1) fg_convT_k<8><<<dim3(NPIX / 256, NB), 256, 0, stream>>>(y, psum, psq, bn_g, bn_b, awf, abf, awg, abg, fqT, gqT, Co);
    else             fg_convT_k<12><<<dim3(NPIX / 256, NB), 256, 0, stream>>>(y, psum, psq, bn_g, bn_b, awf, abf, awg, abg, fqT, gqT, Co);

    conv_bf16_k<<<dim3(8, Co / 2, NB), 256, 0, stream>>>(y, psum, psq, bn_g, bn_b, awh, abh, hq, Co, Co);

    dim3 ag(NPIX / 128, MS, NB);
    if (Co == 32) {
      attn_mfma_k<32><<<ag, 256, 0, stream>>>(fqT, gqT, hq, pacc, pl);
      attn_combine2_k<32><<<(NB * 32 * NPIX) / 1024, 256, 0, stream>>>(pacc, pl, y, psum, psq, bn_g, bn_b, gam, xo);
    } else if (Co == 64) {
      attn_mfma_k<64><<<ag, 256, 0, stream>>>(fqT, gqT, hq, pacc, pl);
      attn_combine2_k<64><<<(NB * 64 * NPIX) / 1024, 256, 0, stream>>>(pacc, pl, y, psum, psq, bn_g, bn_b, gam, xo);
    } else {
      attn_mfma_k<96><<<ag, 256, 0, stream>>>(fqT, gqT, hq, pacc, pl);
      attn_combine2_k<96><<<(NB * 96 * NPIX) / 1024, 256, 0, stream>>>(pacc, pl, y, psum, psq, bn_g, bn_b, gam, xo);
    }
    cur = xo;
  }

  // final: conv(96->512, no bias) + stats, then BN+ReLU+GAP
  conv_stats_k<8, 2><<<dim3(8, 512 / 8, NB), 256, 0, stream>>>(cur, wfin, nullptr, y, psum, psq, 96, 512);
  bn_relu_gap_k<<<dim3(512, NB), 256, 0, stream>>>(y, psum, psq, bnfg, bnfb, (float*)d_out, 512);
}

// Round 10
// 168.658 us; speedup vs baseline: 1.5745x; 1.2740x over previous
//
#include <hip/hip_runtime.h>
#include <hip/hip_bf16.h>

constexpr int NPIX = 4096;   // H*W
constexpr int NB   = 2;      // batch
constexpr int MS   = 8;      // m-split for attention (grid.y)
constexpr int NPART  = 16;   // BN partials per channel

typedef __attribute__((ext_vector_type(8))) short bf16x8;
typedef __attribute__((ext_vector_type(4))) float f32x4;

__device__ inline float bf2f(unsigned short u) {
  unsigned v = (unsigned)u << 16;
  return __builtin_bit_cast(float, v);
}

// ---------------------------------------------------------------------------
// Per-channel fused BN affine from partials: sc = rstd*g, sb = bb - mean*sc
// ---------------------------------------------------------------------------
__device__ inline float2 bn_coeff(const float* __restrict__ psum, const float* __restrict__ psq,
                                  const float* __restrict__ g, const float* __restrict__ bb, int c) {
  float s = 0.f, s2 = 0.f;
#pragma unroll
  for (int p = 0; p < NPART; ++p) {
    s  += psum[(size_t)c * NPART + p];
    s2 += psq [(size_t)c * NPART + p];
  }
  const float inv = 1.f / (NB * NPIX);
  float m = s * inv;
  float var = s2 * inv - m * m;
  float r = rsqrtf(var + 1e-5f) * g[c];
  return float2{r, bb[c] - m * r};
}

// ---------------------------------------------------------------------------
// conv1x1 fp32 + fused BN partial stats.
// CPT out-channels x PX pixels per thread. grid = (NPIX/(256*PX), Co/CPT, NB).
// ---------------------------------------------------------------------------
template <int CPT, int PX>
__global__ __launch_bounds__(256) void conv_stats_k(
    const float* __restrict__ x, const float* __restrict__ w,
    const float* __restrict__ bias, float* __restrict__ y,
    float* __restrict__ psum, float* __restrict__ psq, int Ci, int Co) {
  constexpr int XB = NPIX / (256 * PX);
  const int t  = threadIdx.x;
  const int n  = (blockIdx.x * 256 + t) * PX;
  const int d0 = blockIdx.y * CPT;
  const int b  = blockIdx.z;
  float a[CPT][PX];
#pragma unroll
  for (int j = 0; j < CPT; ++j) {
    float bv = bias ? bias[d0 + j] : 0.f;
#pragma unroll
    for (int p = 0; p < PX; ++p) a[j][p] = bv;
  }
  const float* xb = x + ((size_t)b * Ci) * NPIX + n;
  const float* wr = w + d0;
#pragma unroll 2
  for (int c = 0; c < Ci; ++c) {
    float xv[PX];
    if constexpr (PX == 2) *(float2*)xv = *(const float2*)(xb + (size_t)c * NPIX);
    else                   *(float4*)xv = *(const float4*)(xb + (size_t)c * NPIX);
#pragma unroll
    for (int j = 0; j < CPT; ++j) {
      float wj = wr[j];
#pragma unroll
      for (int p = 0; p < PX; ++p) a[j][p] += xv[p] * wj;
    }
    wr += Co;
  }
  float* yb = y + ((size_t)b * Co + d0) * NPIX + n;
#pragma unroll
  for (int j = 0; j < CPT; ++j) {
    if constexpr (PX == 2) *(float2*)(yb + (size_t)j * NPIX) = *(float2*)a[j];
    else                   *(float4*)(yb + (size_t)j * NPIX) = *(float4*)a[j];
  }

  float s[CPT], s2[CPT];
#pragma unroll
  for (int j = 0; j < CPT; ++j) {
    s[j] = 0.f; s2[j] = 0.f;
#pragma unroll
    for (int p = 0; p < PX; ++p) { s[j] += a[j][p]; s2[j] += a[j][p] * a[j][p]; }
  }
#pragma unroll
  for (int j = 0; j < CPT; ++j) {
    for (int d = 1; d < 64; d <<= 1) {
      s[j]  += __shfl_xor(s[j], d);
      s2[j] += __shfl_xor(s2[j], d);
    }
  }
  __shared__ float shA[4][CPT];
  __shared__ float shB[4][CPT];
  const int wave = t >> 6, lane = t & 63;
  if (lane == 0) {
#pragma unroll
    for (int j = 0; j < CPT; ++j) { shA[wave][j] = s[j]; shB[wave][j] = s2[j]; }
  }
  __syncthreads();
  if (t < CPT) {
    const int p = b * XB + blockIdx.x;
    psum[(size_t)(d0 + t) * NPART + p] = (shA[0][t] + shA[1][t]) + (shA[2][t] + shA[3][t]);
    psq [(size_t)(d0 + t) * NPART + p] = (shB[0][t] + shB[1][t]) + (shB[2][t] + shB[3][t]);
  }
}

// ---------------------------------------------------------------------------
// Fused q/k/v producer. BN+ReLU of y inline (coeffs from partials).
// blockIdx.y slices:
//   [0, Co/2)          : h conv, 2 channels x 2 pixels -> h3 [B][N/32][CO][32]
//   [Co/2, Co/2+CF)    : one f-channel + one g-channel x 2 pixels -> fqT/gqT
//   Co/2+CF            : zero the channel pads [CF,32) of fqT/gqT
// grid = (8, Co/2+CF+1, NB), 256 threads.
// ---------------------------------------------------------------------------
template <int CF>
__global__ __launch_bounds__(256) void qkv_k(
    const float* __restrict__ y,
    const float* __restrict__ psum, const float* __restrict__ psq,
    const float* __restrict__ bn_g, const float* __restrict__ bn_b,
    const float* __restrict__ wh, const float* __restrict__ bh,
    const float* __restrict__ wf, const float* __restrict__ bfv,
    const float* __restrict__ wg, const float* __restrict__ bgv,
    __hip_bfloat16* __restrict__ h3, __hip_bfloat16* __restrict__ fqT,
    __hip_bfloat16* __restrict__ gqT, int Ci, int Co) {
  const int t = threadIdx.x;
  const int n = (blockIdx.x * 256 + t) * 2;
  const int b = blockIdx.z;
  const int slice = blockIdx.y;

  if (slice == Co / 2 + CF) {   // pad-zero slice
#pragma unroll
    for (int px = 0; px < 2; ++px) {
      __hip_bfloat16* fp = fqT + (((size_t)b * NPIX + n + px) << 5);
      __hip_bfloat16* gp = gqT + (((size_t)b * NPIX + n + px) << 5);
      for (int j = CF; j < 32; j += 2) {
        *(unsigned*)(fp + j) = 0u;
        *(unsigned*)(gp + j) = 0u;
      }
    }
    return;
  }

  __shared__ float s_sc[96];
  __shared__ float s_sb[96];
  for (int c = t; c < Ci; c += 256) {
    float2 cf = bn_coeff(psum, psq, bn_g, bn_b, c);
    s_sc[c] = cf.x; s_sb[c] = cf.y;
  }
  __syncthreads();

  const float* xb = y + ((size_t)b * Ci) * NPIX + n;

  if (slice < Co / 2) {         // h path
    const int d0 = slice * 2;
    float2 a0 = {bh[d0], bh[d0]};
    float2 a1 = {bh[d0 + 1], bh[d0 + 1]};
    const float* wr = wh + d0;
#pragma unroll 4
    for (int c = 0; c < Ci; ++c) {
      float2 xv = *(const float2*)(xb + (size_t)c * NPIX);
      float s = s_sc[c], o = s_sb[c];
      xv.x = fmaxf(xv.x * s + o, 0.f);
      xv.y = fmaxf(xv.y * s + o, 0.f);
      float w0 = wr[0], w1 = wr[1];
      a0.x += xv.x * w0; a0.y += xv.y * w0;
      a1.x += xv.x * w1; a1.y += xv.y * w1;
      wr += Co;
    }
    __hip_bfloat16* yb = h3 + ((size_t)(b * (NPIX / 32) + (n >> 5)) * Co + d0) * 32 + (n & 31);
    __hip_bfloat162 t0, t1;
    t0.x = __float2bfloat16(a0.x); t0.y = __float2bfloat16(a0.y);
    t1.x = __float2bfloat16(a1.x); t1.y = __float2bfloat16(a1.y);
    *(unsigned*)yb        = *(unsigned*)&t0;
    *(unsigned*)(yb + 32) = *(unsigned*)&t1;
  } else {                      // f/g path: one channel j of each
    const int j = slice - Co / 2;
    float f0 = bfv[j], f1 = bfv[j], g0 = bgv[j], g1 = bgv[j];
#pragma unroll 4
    for (int c = 0; c < Ci; ++c) {
      float2 xv = *(const float2*)(xb + (size_t)c * NPIX);
      float s = s_sc[c], o = s_sb[c];
      xv.x = fmaxf(xv.x * s + o, 0.f);
      xv.y = fmaxf(xv.y * s + o, 0.f);
      float wfv = wf[(size_t)c * CF + j], wgv = wg[(size_t)c * CF + j];
      f0 += xv.x * wfv; f1 += xv.y * wfv;
      g0 += xv.x * wgv; g1 += xv.y * wgv;
    }
    fqT[(((size_t)b * NPIX + n)     << 5) + j] = __float2bfloat16(f0);
    fqT[(((size_t)b * NPIX + n + 1) << 5) + j] = __float2bfloat16(f1);
    gqT[(((size_t)b * NPIX + n)     << 5) + j] = __float2bfloat16(g0);
    gqT[(((size_t)b * NPIX + n + 1) << 5) + j] = __float2bfloat16(g1);
  }
}

// ---------------------------------------------------------------------------
// MFMA flash attention partial, wave-per-32q, no barriers.
// h3 layout -> coalesced hv; hv prefetched at tile start; bf16 pacc.
// Grid: (NPIX/128, MS, NB), 256 threads. pacc [MS][B][CO][N] bf16, pl fp32.
// ---------------------------------------------------------------------------
template <int CO>
__global__ __launch_bounds__(256) void attn_mfma_k(
    const __hip_bfloat16* __restrict__ fqT, const __hip_bfloat16* __restrict__ gqT,
    const __hip_bfloat16* __restrict__ hq,
    __hip_bfloat16* __restrict__ pacc, float* __restrict__ pl) {
  constexpr int CSUB = CO / 16;
  __shared__ __align__(16) unsigned short Pw[4][2][32][64];   // 32 KB, XOR-swizzled

  const int t = threadIdx.x;
  const int wave = t >> 6, lane = t & 63, lq = lane & 15, lg = lane >> 4;
  const int ms = blockIdx.y, b = blockIdx.z;
  const int q0 = blockIdx.x * 128 + wave * 32;

  bf16x8 ff[2];
#pragma unroll
  for (int qs = 0; qs < 2; ++qs)
    ff[qs] = *reinterpret_cast<const bf16x8*>(
        fqT + (((size_t)b * NPIX + q0 + qs * 16 + lq) << 5) + lg * 8);

  f32x4 acc[2][CSUB];
#pragma unroll
  for (int qs = 0; qs < 2; ++qs)
#pragma unroll
    for (int cs = 0; cs < CSUB; ++cs) acc[qs][cs] = f32x4{0.f, 0.f, 0.f, 0.f};
  float ls[2] = {0.f, 0.f};

  const __hip_bfloat16* h3b = hq + (size_t)b * (NPIX / 32) * CO * 32;
  const int mbeg = ms * (NPIX / MS);

  for (int tile = 0; tile < (NPIX / MS) / 64; ++tile) {
    const int mt = mbeg + tile * 64;
    char* Pb = (char*)&Pw[wave][tile & 1][0][0];

    bf16x8 hv[2][CSUB];
#pragma unroll
    for (int kc = 0; kc < 2; ++kc)
#pragma unroll
      for (int cs = 0; cs < CSUB; ++cs)
        hv[kc][cs] = *reinterpret_cast<const bf16x8*>(
            h3b + ((size_t)((mt >> 5) + kc) * CO + cs * 16 + lq) * 32 + lg * 8);

#pragma unroll
    for (int msub = 0; msub < 4; ++msub) {
      bf16x8 ga = *reinterpret_cast<const bf16x8*>(
          gqT + (((size_t)b * NPIX + mt + msub * 16 + lq) << 5) + lg * 8);
#pragma unroll
      for (int qs = 0; qs < 2; ++qs) {
        f32x4 z = {0.f, 0.f, 0.f, 0.f};
        f32x4 S = __builtin_amdgcn_mfma_f32_16x16x32_bf16(ga, ff[qs], z, 0, 0, 0);
        float p0 = __expf(fminf(S[0], 60.f));
        float p1 = __expf(fminf(S[1], 60.f));
        float p2 = __expf(fminf(S[2], 60.f));
        float p3 = __expf(fminf(S[3], 60.f));
        ls[qs] += (p0 + p1) + (p2 + p3);
        __hip_bfloat162 t0, t1;
        t0.x = __float2bfloat16(p0); t0.y = __float2bfloat16(p1);
        t1.x = __float2bfloat16(p2); t1.y = __float2bfloat16(p3);
        uint2 wv;
        wv.x = *(unsigned*)&t0; wv.y = *(unsigned*)&t1;
        const int row = qs * 16 + lq;
        int byte = row * 128 + msub * 32 + lg * 8;
        byte ^= (row & 7) << 4;
        *(uint2*)(Pb + byte) = wv;
      }
    }
#pragma unroll
    for (int kc = 0; kc < 2; ++kc) {
      bf16x8 pa[2];
#pragma unroll
      for (int qs = 0; qs < 2; ++qs) {
        const int row = qs * 16 + lq;
        int byte = row * 128 + kc * 64 + lg * 16;
        byte ^= (row & 7) << 4;
        pa[qs] = *reinterpret_cast<const bf16x8*>(Pb + byte);
      }
#pragma unroll
      for (int cs = 0; cs < CSUB; ++cs)
#pragma unroll
        for (int qs = 0; qs < 2; ++qs)
          acc[qs][cs] = __builtin_amdgcn_mfma_f32_16x16x32_bf16(pa[qs], hv[kc][cs], acc[qs][cs], 0, 0, 0);
    }
  }

#pragma unroll
  for (int qs = 0; qs < 2; ++qs) {
    ls[qs] += __shfl_xor(ls[qs], 16);
    ls[qs] += __shfl_xor(ls[qs], 32);
  }
  const size_t lbase = ((size_t)ms * NB + b) * NPIX;
  if (lane < 16) {
    pl[lbase + q0 + lq]      = ls[0];
    pl[lbase + q0 + 16 + lq] = ls[1];
  }

  // bf16 pacc: c = cs*16+lq, q = q0+qs*16+4*lg+r (4 consecutive -> uint2)
  const size_t obase = (((size_t)ms * NB + b) * CO) * NPIX;
#pragma unroll
  for (int qs = 0; qs < 2; ++qs)
#pragma unroll
    for (int cs = 0; cs < CSUB; ++cs) {
      __hip_bfloat162 v0, v1;
      v0.x = __float2bfloat16(acc[qs][cs][0]); v0.y = __float2bfloat16(acc[qs][cs][1]);
      v1.x = __float2bfloat16(acc[qs][cs][2]); v1.y = __float2bfloat16(acc[qs][cs][3]);
      uint2 st; st.x = *(unsigned*)&v0; st.y = *(unsigned*)&v1;
      *(uint2*)&pacc[obase + (size_t)(cs * 16 + lq) * NPIX + q0 + qs * 16 + 4 * lg] = st;
    }
}

// ---------------------------------------------------------------------------
// Attention combine: merge MS bf16 partials, normalize, gamma + residual
// (BN+ReLU of y inline). 4 pixels/thread.
// ---------------------------------------------------------------------------
template <int CO>
__global__ __launch_bounds__(256) void attn_combine2_k(
    const __hip_bfloat16* __restrict__ pacc, const float* __restrict__ pl,
    const float* __restrict__ y,
    const float* __restrict__ psum, const float* __restrict__ psq,
    const float* __restrict__ bn_g, const float* __restrict__ bn_b,
    const float* __restrict__ gam, float* __restrict__ xout) {
  int i4 = blockIdx.x * 256 + threadIdx.x;   // over NB*CO*NPIX/4
  int n  = (i4 & 1023) * 4;
  int bc = i4 >> 10;
  int b  = bc / CO, c = bc - b * CO;
  float4 o = {0.f, 0.f, 0.f, 0.f};
  float4 L = {0.f, 0.f, 0.f, 0.f};
#pragma unroll
  for (int m = 0; m < MS; ++m) {
    ushort4 pa = *(const ushort4*)&pacc[(((size_t)m * NB + b) * CO + c) * NPIX + n];
    float4 lv = *(const float4*)&pl[((size_t)m * NB + b) * NPIX + n];
    o.x += bf2f(pa.x); o.y += bf2f(pa.y); o.z += bf2f(pa.z); o.w += bf2f(pa.w);
    L.x += lv.x; L.y += lv.y; L.z += lv.z; L.w += lv.w;
  }
  float2 cf = bn_coeff(psum, psq, bn_g, bn_b, c);
  size_t xi = ((size_t)b * CO + c) * NPIX + n;
  float4 yv = *(const float4*)&y[xi];
  float gm = gam[0];
  float4 r;
  r.x = gm * (o.x / L.x) + fmaxf(yv.x * cf.x + cf.y, 0.f);
  r.y = gm * (o.y / L.y) + fmaxf(yv.y * cf.x + cf.y, 0.f);
  r.z = gm * (o.z / L.z) + fmaxf(yv.z * cf.x + cf.y, 0.f);
  r.w = gm * (o.w / L.w) + fmaxf(yv.w * cf.x + cf.y, 0.f);
  *(float4*)&xout[xi] = r;
}

// ---------------------------------------------------------------------------
// Final: BN apply + ReLU + GAP (float4); coeff computed inline per block.
// ---------------------------------------------------------------------------
__global__ __launch_bounds__(256) void bn_relu_gap_k(
    const float* __restrict__ y,
    const float* __restrict__ psum, const float* __restrict__ psq,
    const float* __restrict__ bn_g, const float* __restrict__ bn_b,
    float* __restrict__ out, int C) {
  int d = blockIdx.x;
  int b = blockIdx.y;
  int tid = threadIdx.x;
  float2 cf = bn_coeff(psum, psq, bn_g, bn_b, d);
  const float* yr = y + ((size_t)b * C + d) * NPIX;
  float s = 0.f;
  for (int n4 = tid; n4 < NPIX / 4; n4 += 256) {
    float4 v = *(const float4*)&yr[n4 * 4];
    s += fmaxf(v.x * cf.x + cf.y, 0.f) + fmaxf(v.y * cf.x + cf.y, 0.f) +
         fmaxf(v.z * cf.x + cf.y, 0.f) + fmaxf(v.w * cf.x + cf.y, 0.f);
  }
  __shared__ float sh[256];
  sh[tid] = s;
  __syncthreads();
  for (int st = 128; st > 0; st >>= 1) {
    if (tid < st) sh[tid] += sh[tid + st];
    __syncthreads();
  }
  if (tid == 0) out[(size_t)b * C + d] = sh[0] * (1.f / NPIX);
}

// ---------------------------------------------------------------------------
// Host side
// ---------------------------------------------------------------------------
extern "C" void kernel_launch(void* const* d_in, const int* in_sizes, int n_in,
                              void* d_out, int out_size, void* d_ws, size_t ws_size,
                              hipStream_t stream) {
  const float* x    = (const float*)d_in[0];
  const float* wfin = (const float*)d_in[34];
  const float* bnfg = (const float*)d_in[35];
  const float* bnfb = (const float*)d_in[36];

  float* ws = (float*)d_ws;
  size_t off = 0;
  float* y    = ws + off; off += (size_t)NB * 512 * NPIX;
  float* xo   = ws + off; off += (size_t)NB * 96 * NPIX;
  __hip_bfloat16* fqT = (__hip_bfloat16*)(ws + off); off += (size_t)NB * NPIX * 16;
  __hip_bfloat16* gqT = (__hip_bfloat16*)(ws + off); off += (size_t)NB * NPIX * 16;
  __hip_bfloat16* hq  = (__hip_bfloat16*)(ws + off); off += (size_t)NB * 48 * NPIX;
  float* psum = ws + off; off += 512 * NPART;
  float* psq  = ws + off; off += 512 * NPART;
  float* pl   = ws + off; off += (size_t)MS * NB * NPIX;
  __hip_bfloat16* pacc = (__hip_bfloat16*)(ws + off); off += (size_t)MS * NB * NPIX * 96 / 2;

  const int Ci_arr[3] = {3, 32, 64};
  const int Co_arr[3] = {32, 64, 96};
  const float* cur = x;
  for (int i = 0; i < 3; ++i) {
    const float* const* p = (const float* const*)(d_in + 1 + i * 11);
    const float* w     = p[0];
    const float* bconv = p[1];
    const float* bn_g  = p[2];
    const float* bn_b  = p[3];
    const float* awf   = p[4];
    const float* abf   = p[5];
    const float* awg   = p[6];
    const float* abg   = p[7];
    const float* awh   = p[8];
    const float* abh   = p[9];
    const float* gam   = p[10];
    int Ci = Ci_arr[i], Co = Co_arr[i];
    int CF = Co / 8;

    conv_stats_k<2, 2><<<dim3(8, Co / 2, NB), 256, 0, stream>>>(cur, w, bconv, y, psum, psq, Ci, Co);

    dim3 qg(8, Co / 2 + CF + 1, NB);
    if (i == 0)      qkv_k<4><<<qg, 256, 0, stream>>>(y, psum, psq, bn_g, bn_b, awh, abh, awf, abf, awg, abg, hq, fqT, gqT, Ci == 3 ? 32 : Ci, Co);
    else if (i == 1) qkv_k<8><<<qg, 256, 0, stream>>>(y, psum, psq, bn_g, bn_b, awh, abh, awf, abf, awg, abg, hq, fqT, gqT, Co == 64 ? 64 : Ci, Co);
    else             qkv_k<12><<<qg, 256, 0, stream>>>(y, psum, psq, bn_g, bn_b, awh, abh, awf, abf, awg, abg, hq, fqT, gqT, 96, Co);

    dim3 ag(NPIX / 128, MS, NB);
    if (Co == 32) {
      attn_mfma_k<32><<<ag, 256, 0, stream>>>(fqT, gqT, hq, pacc, pl);
      attn_combine2_k<32><<<(NB * 32 * NPIX) / 1024, 256, 0, stream>>>(pacc, pl, y, psum, psq, bn_g, bn_b, gam, xo);
    } else if (Co == 64) {
      attn_mfma_k<64><<<ag, 256, 0, stream>>>(fqT, gqT, hq, pacc, pl);
      attn_combine2_k<64><<<(NB * 64 * NPIX) / 1024, 256, 0, stream>>>(pacc, pl, y, psum, psq, bn_g, bn_b, gam, xo);
    } else {
      attn_mfma_k<96><<<ag, 256, 0, stream>>>(fqT, gqT, hq, pacc, pl);
      attn_combine2_k<96><<<(NB * 96 * NPIX) / 1024, 256, 0, stream>>>(pacc, pl, y, psum, psq, bn_g, bn_b, gam, xo);
    }
    cur = xo;
  }

  // final: conv(96->512, no bias) + stats, then BN+ReLU+GAP
  conv_stats_k<8, 2><<<dim3(8, 512 / 8, NB), 256, 0, stream>>>(cur, wfin, nullptr, y, psum, psq, 96, 512);
  bn_relu_gap_k<<<dim3(512, NB), 256, 0, stream>>>(y, psum, psq, bnfg, bnfb, (float*)d_out, 512);
}